// Round 8
// baseline (78.852 us; speedup 1.0000x reference)
//
#include <hip/hip_runtime.h>

#define GRID 1024          // pair-kernel blocks
#define PBLK 512           // pair-kernel threads (8 waves)
#define RT   16            // a-values per thread: PBLK*RT = 8192 = N
#define BCH  8             // b-columns per block (N/GRID = 8)

#define LOG2E 1.4426950408889634f
#define LN2   0.6931471805599453
#define BIGF  1.0e30f      // mask bias; masked pair -> max term 0, factor 1

__device__ __forceinline__ float fast_exp2(float x) {
#if __has_builtin(__builtin_amdgcn_exp2f)
    return __builtin_amdgcn_exp2f(x);      // v_exp_f32
#else
    return exp2f(x);
#endif
}
__device__ __forceinline__ float fast_log2(float x) {
#if __has_builtin(__builtin_amdgcn_logf)
    return __builtin_amdgcn_logf(x);       // v_log_f32
#else
    return log2f(x);
#endif
}

// ---------------------------------------------------------------------------
//   sum_{a,b} [ty[a]==1][ty[b]==0] * softplus(v[b]-v[a])
// 2-node minimal structure: no compaction, no memset, no atomics.
// Both masks are FREE via bias values:
//   a-side: pa = ty==1 ? v*log2e : +1e30   (x ~ -1e30 -> max 0, factor 1)
//   b-side: vb = ty==0 ? v*log2e : -1e30   (same, applied to whole column)
// => every block does IDENTICAL work (8 uniform columns x 16 reg-iters),
// zero branches, zero divergence, zero imbalance (r4's wave-uniform skip
// gave Binomial(8,1/2) per-block work -> ~1.5x tail; this doesn't).
// Log2 domain + product trick: per column one v_log for 16 pairs
// (factors in (1,2], p <= 2^16). Inner iter: sub, max, add, exp2(src-mod
// folded -|x|), fmac = ~16 cy/wave. ~2.1K cy/wave total at 8 waves/SIMD.
// Deterministic: partials[bid] written unconditionally, no init needed.
// ---------------------------------------------------------------------------
__global__ __launch_bounds__(PBLK) void pair_kernel(
        const float* __restrict__ v,
        const int* __restrict__ ty,
        float* __restrict__ partials,
        int N) {
    const int tid = threadIdx.x;

    // Register-resident a-slice (float4/int4 coalesced), bias-masked.
    float pa[RT];
    const float4* v4 = (const float4*)v;
    const int4*   t4 = (const int4*)ty;
    const int nq = N >> 2;                 // float4 count
    #pragma unroll
    for (int j = 0; j < RT / 4; ++j) {
        const int q = j * PBLK + tid;      // float4 index
        if (q < nq) {
            const float4 vv = v4[q];
            const int4   tt = t4[q];
            pa[4*j+0] = (tt.x == 1) ? vv.x * LOG2E : BIGF;
            pa[4*j+1] = (tt.y == 1) ? vv.y * LOG2E : BIGF;
            pa[4*j+2] = (tt.z == 1) ? vv.z * LOG2E : BIGF;
            pa[4*j+3] = (tt.w == 1) ? vv.w * LOG2E : BIGF;
        } else {
            pa[4*j+0] = BIGF; pa[4*j+1] = BIGF;
            pa[4*j+2] = BIGF; pa[4*j+3] = BIGF;
        }
    }

    float accm = 0.0f;   // sum of max(x2,0) terms
    float accl = 0.0f;   // sum of log2(prod) terms

    for (int b0 = blockIdx.x; b0 < N; b0 += GRID * BCH) {
        // Prefetch the block's uniform column values, bias-masked:
        // ty[b]!=0 (or OOB) -> -BIGF -> whole column contributes exactly 0.
        float vb[BCH];
        #pragma unroll
        for (int k = 0; k < BCH; ++k) {
            const int b  = b0 + k * GRID;
            const bool on = (b < N) && (ty[b] == 0);
            vb[k] = on ? v[b] * LOG2E : -BIGF;
        }
        #pragma unroll
        for (int k = 0; k < BCH; ++k) {
            const float vbl = vb[k];
            float p = 1.0f;
            #pragma unroll
            for (int r = 0; r < RT; ++r) {
                const float x = vbl - pa[r];
                accm += fmaxf(x, 0.0f);
                const float e = fast_exp2(-fabsf(x));   // src mods fold
                p = fmaf(p, e, p);                      // p *= (1 + e)
            }
            accl += fast_log2(p);                       // 1 trans / 16 pairs
        }
    }

    float acc = accm + accl;

    // wave reduce, then cross-wave via LDS
    for (int off = 32; off > 0; off >>= 1)
        acc += __shfl_down(acc, off, 64);

    __shared__ float wsum[PBLK / 64];
    const int lane = tid & 63;
    const int wid  = tid >> 6;
    if (lane == 0) wsum[wid] = acc;
    __syncthreads();
    if (tid == 0) {
        float s = 0.0f;
        #pragma unroll
        for (int wdx = 0; wdx < PBLK / 64; ++wdx) s += wsum[wdx];
        partials[blockIdx.x] = s;            // unconditional
    }
}

// ---------------------------------------------------------------------------
// Single block: total = sum(partials); P,Q counted straight from ty;
// out = ln2 * total / (P*Q).
// ---------------------------------------------------------------------------
__global__ __launch_bounds__(PBLK) void finalize_kernel(
        const float* __restrict__ partials, int nparts,
        const int* __restrict__ ty, int N,
        float* __restrict__ out) {
    const int tid = threadIdx.x;

    double s = 0.0;
    for (int k = tid; k < nparts; k += PBLK) s += (double)partials[k];

    int cp = 0, cn = 0;
    for (int k = tid; k < N; k += PBLK) {
        const int t = ty[k];
        cp += (t == 1);
        cn += (t == 0);
    }

    __shared__ double sd[PBLK];
    __shared__ int    sp_[PBLK];
    __shared__ int    sn_[PBLK];
    sd[tid] = s; sp_[tid] = cp; sn_[tid] = cn;
    __syncthreads();
    for (int off = PBLK / 2; off > 0; off >>= 1) {
        if (tid < off) {
            sd[tid]  += sd[tid + off];
            sp_[tid] += sp_[tid + off];
            sn_[tid] += sn_[tid + off];
        }
        __syncthreads();
    }
    if (tid == 0) {
        const double denom = (double)sp_[0] * (double)sn_[0];
        out[0] = (float)(sd[0] * LN2 / denom);
    }
}

extern "C" void kernel_launch(void* const* d_in, const int* in_sizes, int n_in,
                              void* d_out, int out_size, void* d_ws, size_t ws_size,
                              hipStream_t stream) {
    const float* v  = (const float*)d_in[0];   // pred_y fp32, N = n*K = 8192
    const int*   ty = (const int*)d_in[1];     // true_y int32 {0,1}
    float* out = (float*)d_out;
    const int N = in_sizes[0];

    float* partials = (float*)d_ws;            // GRID floats, fully overwritten

    pair_kernel<<<GRID, PBLK, 0, stream>>>(v, ty, partials, N);
    finalize_kernel<<<1, PBLK, 0, stream>>>(partials, GRID, ty, N, out);
}

// Round 9
// 69.473 us; speedup vs baseline: 1.1350x; 1.1350x over previous
//
#include <hip/hip_runtime.h>

#define CBLK 256
#define GRID 1024          // pair-kernel blocks
#define PBLK 512           // pair-kernel threads (8 waves)
#define RT   9             // pos per thread per chunk: 512*9 = 4608 >= P (mean+11 sigma)

#define LOG2E 1.4426950408889634f
#define LN2   0.6931471805599453
#define BIGF  1.0e30f      // mask bias: x=-1e30 -> max term 0, exp2(-|x|)=0, factor 1

__device__ __forceinline__ float fast_exp2(float x) {
#if __has_builtin(__builtin_amdgcn_exp2f)
    return __builtin_amdgcn_exp2f(x);      // v_exp_f32
#else
    return exp2f(x);
#endif
}
__device__ __forceinline__ float fast_log2(float x) {
#if __has_builtin(__builtin_amdgcn_logf)
    return __builtin_amdgcn_logf(x);       // v_log_f32
#else
    return log2f(x);
#endif
}

// ---------------------------------------------------------------------------
// Pass 1: compact pred*log2(e) into dense vpos[] (ty==1) / vneg[] (ty==0).
// Ballot-based wave compaction, one atomic per wave per list.
// cnt[0]=P, cnt[1]=Q (zeroed by the 8-byte memset node).
// ---------------------------------------------------------------------------
__global__ void compact_kernel(const float* __restrict__ v,
                               const int* __restrict__ ty,
                               int* __restrict__ cnt,
                               float* __restrict__ vpos,
                               float* __restrict__ vneg,
                               int N) {
    const int i    = blockIdx.x * blockDim.x + threadIdx.x;
    const int lane = threadIdx.x & 63;

    const bool valid = (i < N);
    float val = 0.0f;
    int   t   = -1;
    if (valid) { val = v[i] * LOG2E; t = ty[i]; }

    const bool isP = valid && (t == 1);
    const bool isN = valid && (t == 0);

    const unsigned long long mp = __ballot(isP);
    const unsigned long long mn = __ballot(isN);
    const unsigned long long lt = (lane == 0) ? 0ull : (~0ull >> (64 - lane));

    int basep = 0, basen = 0;
    if (lane == 0) {
        basep = atomicAdd(&cnt[0], __popcll(mp));
        basen = atomicAdd(&cnt[1], __popcll(mn));
    }
    basep = __shfl(basep, 0, 64);
    basen = __shfl(basen, 0, 64);

    if (isP) vpos[basep + __popcll(mp & lt)] = val;
    if (isN) vneg[basen + __popcll(mn & lt)] = val;
}

// ---------------------------------------------------------------------------
// Pass 2: sum over the dense P x Q pair space — no branches, no divergence,
// uniform work per block. Thread holds RT=9 compacted pos values in registers
// (BIGF past P: mask free). Block bid owns dense neg columns b = bid + k*GRID
// (~4 each). Per r-iter: sub, max, add, exp2(-|x|; src mods fold), fmac;
// one v_log per column (product of 9 factors <= 2^9).
// 36 inner iters/thread vs the 32 parallelism floor (16.7M pairs / 524K
// lanes) — pair work is within ~12% of its structural minimum.
// Deterministic: partials[bid] written unconditionally.
// ---------------------------------------------------------------------------
__global__ __launch_bounds__(PBLK) void pair_kernel(
        const int* __restrict__ cnt,
        const float* __restrict__ vpos,
        const float* __restrict__ vneg,
        float* __restrict__ partials) {
    const int P   = cnt[0];
    const int Q   = cnt[1];
    const int tid = threadIdx.x;

    float accm = 0.0f;   // sum of max(x2,0) terms
    float accl = 0.0f;   // sum of log2(prod) terms

    for (int base = 0; base < P; base += RT * PBLK) {   // 1 chunk for P<=4608
        float pa[RT];
        #pragma unroll
        for (int r = 0; r < RT; ++r) {
            const int idx = base + r * PBLK + tid;      // lane-consecutive
            pa[r] = (idx < P) ? vpos[idx] : BIGF;
        }

        for (int b = blockIdx.x; b < Q; b += GRID) {
            const float vbl = vneg[b];                  // uniform -> s_load
            float p = 1.0f;
            #pragma unroll
            for (int r = 0; r < RT; ++r) {
                const float x = vbl - pa[r];
                accm += fmaxf(x, 0.0f);
                const float e = fast_exp2(-fabsf(x));   // src mods fold
                p = fmaf(p, e, p);                      // p *= (1 + e)
            }
            accl += fast_log2(p);                       // 1 trans per 9 pairs
        }
    }

    float acc = accm + accl;

    // wave reduce, then cross-wave via LDS
    for (int off = 32; off > 0; off >>= 1)
        acc += __shfl_down(acc, off, 64);

    __shared__ float wsum[PBLK / 64];
    const int lane = tid & 63;
    const int wid  = tid >> 6;
    if (lane == 0) wsum[wid] = acc;
    __syncthreads();
    if (tid == 0) {
        float s = 0.0f;
        #pragma unroll
        for (int wdx = 0; wdx < PBLK / 64; ++wdx) s += wsum[wdx];
        partials[blockIdx.x] = s;            // unconditional
    }
}

// ---------------------------------------------------------------------------
// Pass 3: out = ln2 * sum(partials) / (P*Q), double accumulation.
// ---------------------------------------------------------------------------
__global__ __launch_bounds__(256) void finalize_kernel(
        const float* __restrict__ partials, int nparts,
        const int* __restrict__ cnt,
        float* __restrict__ out) {
    const int tid = threadIdx.x;
    double s = 0.0;
    for (int k = tid; k < nparts; k += 256) s += (double)partials[k];

    __shared__ double sd[256];
    sd[tid] = s;
    __syncthreads();
    for (int off = 128; off > 0; off >>= 1) {
        if (tid < off) sd[tid] += sd[tid + off];
        __syncthreads();
    }
    if (tid == 0) {
        const double denom = (double)cnt[0] * (double)cnt[1];
        out[0] = (float)(sd[0] * LN2 / denom);
    }
}

extern "C" void kernel_launch(void* const* d_in, const int* in_sizes, int n_in,
                              void* d_out, int out_size, void* d_ws, size_t ws_size,
                              hipStream_t stream) {
    const float* v  = (const float*)d_in[0];   // pred_y fp32, N = n*K = 8192
    const int*   ty = (const int*)d_in[1];     // true_y int32 {0,1}
    float* out = (float*)d_out;
    const int N = in_sizes[0];

    // ws layout: [cnt:2 ints][pad to 64B][vpos:N][vneg:N][partials:GRID]
    char*  ws       = (char*)d_ws;
    int*   cnt      = (int*)ws;
    float* vpos     = (float*)(ws + 64);
    float* vneg     = vpos + N;
    float* partials = vneg + N;

    hipMemsetAsync(cnt, 0, 2 * sizeof(int), stream);   // capturable memset node

    const int cblocks = (N + CBLK - 1) / CBLK;
    compact_kernel<<<cblocks, CBLK, 0, stream>>>(v, ty, cnt, vpos, vneg, N);
    pair_kernel<<<GRID, PBLK, 0, stream>>>(cnt, vpos, vneg, partials);
    finalize_kernel<<<1, 256, 0, stream>>>(partials, GRID, cnt, out);
}